// Round 15
// baseline (746.658 us; speedup 1.0000x reference)
//
#include <hip/hip_runtime.h>

// MLA projection: T=4096, H=7168, N_HEADS=128, QK_NOPE=128, QK_ROPE=64, KV_RANK=512
// out row = [q (128*192=24576) | ckv (512) | k_rope (64)] = 25152 fp32

typedef __attribute__((ext_vector_type(8))) __bf16 bf16x8;
typedef __attribute__((ext_vector_type(4))) float f32x4;

#define OUT_LD 25152

__device__ __forceinline__ unsigned short f2bf(float f) {
  union { float f; unsigned u; } v; v.f = f;
  unsigned r = v.u + 0x7FFFu + ((v.u >> 16) & 1u);  // RNE
  return (unsigned short)(r >> 16);
}

__device__ __forceinline__ void gload16(const void* g, void* l) {
  __builtin_amdgcn_global_load_lds(
      (__attribute__((address_space(1))) void*)(void*)g,
      (__attribute__((address_space(3))) void*)l, 16, 0, 0);
}

// ---- fp32 -> bf16 straight conversion (token_x), 4 elems/thread ----
__global__ void cvt_bf16(const float* __restrict__ in, unsigned short* __restrict__ out) {
  size_t i = (size_t)blockIdx.x * 256 + threadIdx.x;
  float4 f = ((const float4*)in)[i];
  ushort4 o;
  o.x = f2bf(f.x); o.y = f2bf(f.y); o.z = f2bf(f.z); o.w = f2bf(f.w);
  ((ushort4*)out)[i] = o;
}

// ---- fp32 (K x N) -> bf16 (Npad x K) transpose+convert, zero pad rows >= N ----
__global__ void transpose_cvt(const float* __restrict__ in, unsigned short* __restrict__ out,
                              int K, int N, int Npad) {
  __shared__ float tile[32][33];
  int k0 = blockIdx.x * 32, n0 = blockIdx.y * 32;
  int tx = threadIdx.x, ty = threadIdx.y;  // 32 x 8
#pragma unroll
  for (int i = 0; i < 4; ++i) {
    int k = k0 + ty + i * 8;
    int n = n0 + tx;
    tile[ty + i * 8][tx] = (n < N) ? in[(size_t)k * N + n] : 0.f;
  }
  __syncthreads();
#pragma unroll
  for (int i = 0; i < 4; ++i) {
    int n = n0 + ty + i * 8;
    int k = k0 + tx;
    if (n < Npad) out[(size_t)n * K + k] = f2bf(tile[tx][ty + i * 8]);
  }
}

// ======================================================================
// GEMM2 round-15: 128x256 tile, 512 threads (8 waves = 2x4, each 64x64),
// BK=32, dbuf LDS 48 KB -> 2 BLOCKS/CU (16 waves/CU, 4/SIMD). The r4-r14
// campaign showed a 256^2 tile (acc = half the register file) allows only
// 1 block/CU / 2 waves/SIMD: zero TLP, LDS port + MFMA pipe serialize at
// ~6250cy/K-tile regardless of schedule. This kernel restores m97-style
// TLP: simple 1-barrier/K-tile loop; cross-BLOCK overlap hides the port.
// LDS swizzle (64B rows): superrow = 2 rows = 128B = 8 granules;
// stored = logical ^ ((srow&7)<<4); stage source permuted by the same
// involution (G = (parity*4+k16)^(srow&7)) -> conflict-free reads, linear
// gload_lds dests (rule #21). T1 XCD swizzle, T5 setprio, fused q-RoPE.
// A (M,K) k-contig, B (N,K) k-contig, C fp32.
// ======================================================================
__global__ __launch_bounds__(512, 4) void gemm_ht(
    const unsigned short* __restrict__ A, const unsigned short* __restrict__ B,
    float* __restrict__ C, int K, int ldc, int Mtiles,
    const float* __restrict__ cs, const float* __restrict__ sn, int rope) {
  __shared__ __attribute__((aligned(128))) char lds[49152];  // 2 x (A 8KB + B 16KB)
  const int tid = threadIdx.x;
  const int lane = tid & 63;
  const int wr = (tid >> 6) >> 2;  // 0..1
  const int wc = (tid >> 6) & 3;   // 0..3
  const int NT = K >> 5;

  // T1: XCD-aware block swizzle (grid % 8 == 0 by launch)
  const int nwg = gridDim.x;
  const int per = nwg >> 3;
  const int bid = blockIdx.x;
  const int swz = (bid & 7) * per + (bid >> 3);
  const int bm = swz % Mtiles, bn = swz / Mtiles;

  const size_t abase = (size_t)(bm * 128) * K;
  const size_t bbase = (size_t)(bn * 256) * K;

  // ---- staging geometry (superrow swizzle, derivation in header) ----
  // A: 1 unit of 512x16B. thread -> (srow = tid>>3, G = tid&7);
  //    g = G ^ (srow&7); parity = g>>2; k16 = g&3; global row = 2*srow+parity.
  const int sa = tid >> 3;
  const int ga = (tid & 7) ^ (sa & 7);
  const int arow = 2 * sa + (ga >> 2);
  const int acol = (ga & 3) * 8;  // element offset (8 bf16 = 16B)
  // B: 2 units; unit u covers j = u*512+tid.
  const int jb0 = tid, jb1 = 512 + tid;
  const int sb0 = jb0 >> 3, sb1 = jb1 >> 3;
  const int gb0 = (jb0 & 7) ^ (sb0 & 7), gb1 = (jb1 & 7) ^ (sb1 & 7);
  const int brow0 = 2 * sb0 + (gb0 >> 2), brow1 = 2 * sb1 + (gb1 >> 2);
  const int bcol0 = (gb0 & 3) * 8, bcol1 = (gb1 & 3) * 8;

  f32x4 acc[4][4];
  const f32x4 z4 = {0.f, 0.f, 0.f, 0.f};
#pragma unroll
  for (int m = 0; m < 4; ++m)
#pragma unroll
    for (int n = 0; n < 4; ++n) acc[m][n] = z4;

#define STAGE(kt, bsel)                                                              \
  do {                                                                               \
    char* R_ = lds + (bsel) * 24576;                                                 \
    gload16(A + abase + (size_t)arow * K + (size_t)(kt) * 32 + acol, R_ + tid * 16); \
    gload16(B + bbase + (size_t)brow0 * K + (size_t)(kt) * 32 + bcol0,               \
            R_ + 8192 + jb0 * 16);                                                   \
    gload16(B + bbase + (size_t)brow1 * K + (size_t)(kt) * 32 + bcol1,               \
            R_ + 8192 + jb1 * 16);                                                   \
  } while (0)

  // ---- prologue ----
  STAGE(0, 0);
  __syncthreads();

  for (int t = 0; t < NT; ++t) {
    const int buf = t & 1;
    const char* Lb = lds + buf * 24576;
    if (t + 1 < NT) STAGE(t + 1, buf ^ 1);

    bf16x8 af[4], bb[4];
#pragma unroll
    for (int mf = 0; mf < 4; ++mf) {
      int row_ = wr * 64 + mf * 16 + (lane & 15);
      int s_ = row_ >> 1;
      int st_ = (((row_ & 1) * 64 + (lane >> 4) * 16)) ^ ((s_ & 7) << 4);
      af[mf] = *(const bf16x8*)(Lb + s_ * 128 + st_);
    }
#pragma unroll
    for (int nf = 0; nf < 4; ++nf) {
      int n_ = wc * 64 + nf * 16 + (lane & 15);
      int s_ = n_ >> 1;
      int st_ = (((n_ & 1) * 64 + (lane >> 4) * 16)) ^ ((s_ & 7) << 4);
      bb[nf] = *(const bf16x8*)(Lb + 8192 + s_ * 128 + st_);
    }

    __builtin_amdgcn_s_setprio(1);
#pragma unroll
    for (int mf = 0; mf < 4; ++mf)
#pragma unroll
      for (int nf = 0; nf < 4; ++nf)
        acc[mf][nf] = __builtin_amdgcn_mfma_f32_16x16x32_bf16(af[mf], bb[nf], acc[mf][nf], 0, 0, 0);
    __builtin_amdgcn_s_setprio(0);

    __syncthreads();  // drains vmcnt (t+1 staged) + lgkm, one barrier per K-tile
  }
#undef STAGE

  // ---- epilogue: C write, fused RoPE on 64-col rope strips ----
  const int colbase = bn * 256 + wc * 64;
  const int rbase = bm * 128 + wr * 64 + ((lane >> 4) << 2);
  const bool isrope = rope && ((colbase % 192) == 128);
  if (isrope) {
#pragma unroll
    for (int mf = 0; mf < 4; ++mf)
#pragma unroll
      for (int nf = 0; nf < 2; ++nf) {
        int i_ = nf * 16 + (lane & 15);
#pragma unroll
        for (int r = 0; r < 4; ++r) {
          int trow = rbase + mf * 16 + r;
          float c1 = cs[trow * 64 + i_], s1 = sn[trow * 64 + i_];
          float c2 = cs[trow * 64 + 32 + i_], s2 = sn[trow * 64 + 32 + i_];
          float a = acc[mf][nf][r], b = acc[mf][nf + 2][r];
          C[(size_t)trow * ldc + colbase + i_] = a * c1 - b * s1;
          C[(size_t)trow * ldc + colbase + 32 + i_] = b * c2 + a * s2;
        }
      }
  } else {
#pragma unroll
    for (int mf = 0; mf < 4; ++mf)
#pragma unroll
      for (int nf = 0; nf < 4; ++nf)
#pragma unroll
        for (int r = 0; r < 4; ++r) {
          int trow = rbase + mf * 16 + r;
          C[(size_t)trow * ldc + colbase + nf * 16 + (lane & 15)] = acc[mf][nf][r];
        }
  }
}

// ---- 128x128 bf16 GEMM for GEMM1+3 (r14 single-barrier loop) ----
__global__ __launch_bounds__(256, 2) void gemm128(
    const unsigned short* __restrict__ A, const unsigned short* __restrict__ B,
    float* __restrict__ C, int K, int ldc, int Nvalid) {
  __shared__ __attribute__((aligned(128))) unsigned short As[2][128 * 32];
  __shared__ __attribute__((aligned(128))) unsigned short Bs[2][128 * 32];
  const int tid = threadIdx.x;
  const int lane = tid & 63;
  const int wid = tid >> 6;
  const int wr = wid >> 1, wc = wid & 1;
  const int bm = blockIdx.y, bn = blockIdx.x;
  const size_t abase = (size_t)bm * 128 * K;
  const size_t bbase = (size_t)bn * 128 * K;

  f32x4 acc[4][4];
  const f32x4 zero4 = {0.f, 0.f, 0.f, 0.f};
#pragma unroll
  for (int m = 0; m < 4; ++m)
#pragma unroll
    for (int n = 0; n < 4; ++n) acc[m][n] = zero4;

  const int r0 = tid >> 2;
  const int c0 = (tid & 3) * 8;
  const int NT = K >> 5;

#define G128_STAGE(kt, bsel)                                                   \
  do {                                                                         \
    gload16(A + abase + (size_t)r0 * K + (kt) * 32 + c0, As[bsel] + tid * 8);  \
    gload16(A + abase + (size_t)(r0 + 64) * K + (kt) * 32 + c0,                \
            As[bsel] + (256 + tid) * 8);                                       \
    gload16(B + bbase + (size_t)r0 * K + (kt) * 32 + c0, Bs[bsel] + tid * 8);  \
    gload16(B + bbase + (size_t)(r0 + 64) * K + (kt) * 32 + c0,                \
            Bs[bsel] + (256 + tid) * 8);                                       \
  } while (0)

  G128_STAGE(0, 0);
  __syncthreads();

  for (int t = 0; t < NT; ++t) {
    const int buf = t & 1;
    const int pb = buf ^ 1;
    if (t + 1 < NT) G128_STAGE(t + 1, pb);

    bf16x8 af[4], bfr[4];
#pragma unroll
    for (int m = 0; m < 4; ++m)
      af[m] = *(const bf16x8*)(As[buf] + (wr * 64 + m * 16 + (lane & 15)) * 32 + (lane >> 4) * 8);
#pragma unroll
    for (int n = 0; n < 4; ++n)
      bfr[n] = *(const bf16x8*)(Bs[buf] + (wc * 64 + n * 16 + (lane & 15)) * 32 + (lane >> 4) * 8);

    asm volatile("s_waitcnt lgkmcnt(0)" ::: "memory");
    __builtin_amdgcn_sched_barrier(0);
    __builtin_amdgcn_s_setprio(1);
#pragma unroll
    for (int m = 0; m < 4; ++m)
#pragma unroll
      for (int n = 0; n < 4; ++n)
        acc[m][n] = __builtin_amdgcn_mfma_f32_16x16x32_bf16(af[m], bfr[n], acc[m][n], 0, 0, 0);
    __builtin_amdgcn_s_setprio(0);

    __syncthreads();
  }
#undef G128_STAGE

  const int crow0 = bm * 128 + wr * 64 + ((lane >> 4) << 2);
  const int ccol0 = bn * 128 + wc * 64 + (lane & 15);
#pragma unroll
  for (int m = 0; m < 4; ++m) {
#pragma unroll
    for (int n = 0; n < 4; ++n) {
      int col = ccol0 + n * 16;
      if (col < Nvalid) {
#pragma unroll
        for (int r = 0; r < 4; ++r) {
          int row = crow0 + m * 16 + r;
          C[(size_t)row * ldc + col] = acc[m][n][r];
        }
      }
    }
  }
}

// ---- merged stage-1 epilogue: rmsnorm(cq)->bf16, rmsnorm(ckv)+rope(k_rope)->out ----
__global__ void epi1(const float* __restrict__ raw, const float* __restrict__ gcq,
                     const float* __restrict__ gckv, const float* __restrict__ cs,
                     const float* __restrict__ sn, unsigned short* __restrict__ cqb,
                     float* __restrict__ out) {
  __shared__ float red[4];
  int t = blockIdx.x, tid = threadIdx.x;
  const float* r = raw + (size_t)t * 2176;
  float v[6];
  float ss = 0.f;
#pragma unroll
  for (int i = 0; i < 6; ++i) {
    v[i] = r[tid + i * 256];
    ss += v[i] * v[i];
  }
#pragma unroll
  for (int o = 32; o > 0; o >>= 1) ss += __shfl_xor(ss, o, 64);
  if ((tid & 63) == 0) red[tid >> 6] = ss;
  __syncthreads();
  ss = red[0] + red[1] + red[2] + red[3];
  float sc = rsqrtf(ss * (1.f / 1536.f) + 1e-6f);
#pragma unroll
  for (int i = 0; i < 6; ++i)
    cqb[(size_t)t * 1536 + tid + i * 256] = f2bf(v[i] * sc * gcq[tid + i * 256]);
  float v0 = r[1536 + tid], v1 = r[1792 + tid];
  float s2 = v0 * v0 + v1 * v1;
#pragma unroll
  for (int o = 32; o > 0; o >>= 1) s2 += __shfl_xor(s2, o, 64);
  __syncthreads();
  if ((tid & 63) == 0) red[tid >> 6] = s2;
  __syncthreads();
  s2 = red[0] + red[1] + red[2] + red[3];
  float sck = rsqrtf(s2 * (1.f / 512.f) + 1e-6f);
  float* orow = out + (size_t)t * OUT_LD + 24576;
  orow[tid] = v0 * sck * gckv[tid];
  orow[tid + 256] = v1 * sck * gckv[tid + 256];
  if (tid < 32) {
    float a = r[2048 + tid], b = r[2080 + tid];
    orow[512 + tid] = a * cs[t * 64 + tid] - b * sn[t * 64 + tid];
    orow[544 + tid] = b * cs[t * 64 + 32 + tid] + a * sn[t * 64 + 32 + tid];
  }
}

extern "C" void kernel_launch(void* const* d_in, const int* in_sizes, int n_in,
                              void* d_out, int out_size, void* d_ws, size_t ws_size,
                              hipStream_t stream) {
  const float* token_x = (const float*)d_in[0];   // 4096 x 7168
  const float* wq_a = (const float*)d_in[1];      // 7168 x 1536
  const float* wq_b = (const float*)d_in[2];      // 1536 x 24576
  const float* wkv = (const float*)d_in[3];       // 7168 x 576
  const float* rope_cos = (const float*)d_in[4];  // 4096 x 64
  const float* rope_sin = (const float*)d_in[5];
  const float* gamma_cq = (const float*)d_in[6];   // 1536
  const float* gamma_ckv = (const float*)d_in[7];  // 512
  float* out = (float*)d_out;                      // 4096 x 25152

  char* ws = (char*)d_ws;
  unsigned short* txb = (unsigned short*)ws;                          // 4096x7168 bf16
  unsigned short* wqbT = (unsigned short*)(ws + 58720256);            // 24576x1536 bf16
  unsigned short* Bc = (unsigned short*)(ws + 134217728);             // 2176x7168 bf16
  float* raw = (float*)(ws + 165412864);                              // 4096x2176 f32
  unsigned short* cqb = (unsigned short*)(ws + 201064448);            // 4096x1536 bf16

  // 1) conversions
  cvt_bf16<<<28672, 256, 0, stream>>>(token_x, txb);
  transpose_cvt<<<dim3(7168 / 32, 1536 / 32), dim3(32, 8), 0, stream>>>(wq_a, Bc, 7168, 1536, 1536);
  transpose_cvt<<<dim3(7168 / 32, 640 / 32), dim3(32, 8), 0, stream>>>(
      wkv, Bc + (size_t)1536 * 7168, 7168, 576, 640);
  transpose_cvt<<<dim3(1536 / 32, 24576 / 32), dim3(32, 8), 0, stream>>>(wq_b, wqbT, 1536, 24576, 24576);

  // 2) fused GEMM1+GEMM3: raw = token_x @ [wq_a | wkv | 0pad]  (4096 x 2176, K=7168)
  gemm128<<<dim3(17, 32), 256, 0, stream>>>(txb, Bc, raw, 7168, 2176, 2176);

  // 3) merged stage-1 epilogue
  epi1<<<4096, 256, 0, stream>>>(raw, gamma_cq, gamma_ckv, rope_cos, rope_sin, cqb, out);

  // 4) GEMM2 (128x256 tile, 2 blocks/CU TLP, fused rope): q = cq @ wq_b, K=1536
  //    grid = 32 Mtiles * 96 Ntiles = 3072 (% 8 == 0 for XCD swizzle)
  gemm_ht<<<3072, 512, 0, stream>>>(cqb, wqbT, out, 1536, OUT_LD, 32, rope_cos, rope_sin, 1);
}